// Round 19
// baseline (66.816 us; speedup 1.0000x reference)
//
#include <hip/hip_runtime.h>
#include <hip/hip_bf16.h>
#include <math.h>

#define BETA_INV 20.0f          // 1/0.05
#define BG_KNN   50
#define N_CAMS   6
#define CLS      2000
#define DIM      2048
#define BATCH    256
#define NPROXY   (N_CAMS * CLS)     // 12000
#define MASK_VAL -10000.0f
#define NKT      (DIM / 32)         // 64 K-tiles of 32

typedef __attribute__((ext_vector_type(8))) short short8;
typedef __attribute__((ext_vector_type(4))) float f32x4;
typedef __attribute__((address_space(1))) const unsigned int g_u32;
typedef __attribute__((address_space(3))) unsigned int l_u32;

__device__ __forceinline__ uint2 cvt4(float4 v) {
    uint2 r;
    asm("v_cvt_pk_bf16_f32 %0, %1, %2" : "=v"(r.x) : "v"(v.x), "v"(v.y));
    asm("v_cvt_pk_bf16_f32 %0, %1, %2" : "=v"(r.y) : "v"(v.z), "v"(v.w));
    return r;
}

// ---------------- transpose fp32 [rows][2048] -> bf16 MFMA-fragment layout ----------------
// Also zeroes the loss accumulators (block 0) — stream-ordered before per_sample.
__global__ __launch_bounds__(256) void conv_t(const float* __restrict__ src,
                                              unsigned short* __restrict__ dst,
                                              int nrb,          // rows/32
                                              unsigned* __restrict__ accz)  // 13 words
{
    __shared__ unsigned short lds[32][72];
    const int t  = threadIdx.x;
    const int b  = blockIdx.x;
    if (b == 0 && t < 13) accz[t] = 0u;   // 6 float sums + 6 counts + ticket

    const int rb = b % nrb, kb = b / nrb;
    const int r  = t >> 3, c8 = (t & 7) * 8;

    const float* sp = src + (size_t)(rb * 32 + r) * DIM + kb * 64 + c8;
    float4 f0 = *(const float4*)sp;
    float4 f1 = *(const float4*)(sp + 4);
    uint2 pa = cvt4(f0), pb = cvt4(f1);
    *(uint4*)&lds[r][c8] = make_uint4(pa.x, pa.y, pb.x, pb.y);
    __syncthreads();

    const int cidx = t >> 6;
    const int n16h = cidx >> 1, kth = cidx & 1;
    const int lane = t & 63;
    const int fr = lane & 15, kg = lane >> 4;
    uint4 v = *(const uint4*)&lds[n16h * 16 + fr][kth * 32 + kg * 8];
    const size_t N16 = (size_t)rb * 2 + n16h;
    const size_t KT  = (size_t)kb * 2 + kth;
    *(uint4*)(dst + ((N16 * NKT + KT) * 64 + lane) * 8) = v;
}

// ---------------- GEMM: BM=128 x BN=96, FULL K, grid 250, ring-3 depth-2 (R15 best) ----
#define NSTEP 32                // 2048 / 64

__global__ __launch_bounds__(512) void gemm_fullk(const unsigned short* __restrict__ At,
                                                  const float* __restrict__ Bm,   // [12000][2048] f32
                                                  float* __restrict__ C)          // [256][12000]
{
    __shared__ __align__(16) unsigned short ldsA[3][8192];   // 3 x 16KB
    __shared__ __align__(16) float          ldsB[3][6144];   // 3 x 24KB

    const int tid = threadIdx.x;
    const int bid = blockIdx.x;
    const int xcd = bid & 7, pos = bid >> 3;
    const int lid = (xcd < 2 ? xcd * 32 : 64 + (xcd - 2) * 31) + pos;
    const int bm  = (lid & 1) * 128;
    const int bn  = (lid >> 1) * 96;

    const int lane = tid & 63, wid = tid >> 6;
    const int mw = wid >> 1;
    const int nw = wid & 1;
    const int fr = lane & 15, kg = lane >> 4;

    const unsigned short* pAq[2];
    int dA[2];
#pragma unroll
    for (int q = 0; q < 2; ++q) {
        int f = q * 512 + tid;
        int chunk = f >> 6, ln = f & 63;
        int n16l = chunk >> 1, ktl = chunk & 1;
        pAq[q] = At + ((size_t)((bm >> 4) + n16l) * NKT + ktl) * 512 + ln * 8;
        dA[q] = f * 8;                // shorts
    }
    const float* pBq[3];
    int dB[3];
#pragma unroll
    for (int q = 0; q < 3; ++q) {
        int f = q * 512 + tid;
        int row = f >> 4, c = f & 15;
        pBq[q] = Bm + (size_t)(bn + row) * DIM + ((c ^ (row & 15)) * 4);
        dB[q] = f * 4;                // floats
    }

#define STAGE(BUF, T) do {                                                                \
        _Pragma("unroll")                                                                 \
        for (int q = 0; q < 2; ++q)                                                       \
            __builtin_amdgcn_global_load_lds((g_u32*)(pAq[q] + (size_t)(T) * 1024),       \
                                             (l_u32*)&ldsA[BUF][dA[q]], 16, 0, 0);        \
        _Pragma("unroll")                                                                 \
        for (int q = 0; q < 3; ++q)                                                       \
            __builtin_amdgcn_global_load_lds((g_u32*)(pBq[q] + (size_t)(T) * 64),         \
                                             (l_u32*)&ldsB[BUF][dB[q]], 16, 0, 0);        \
    } while (0)

    f32x4 acc[2][3];
#pragma unroll
    for (int i = 0; i < 2; ++i)
#pragma unroll
        for (int j = 0; j < 3; ++j) acc[i][j] = (f32x4){0.f, 0.f, 0.f, 0.f};

#define COMPUTE(CUR) do {                                                                 \
    _Pragma("unroll")                                                                     \
    for (int ks = 0; ks < 2; ++ks) {                                                      \
        short8 bfr[3];                                                                    \
        _Pragma("unroll")                                                                 \
        for (int j = 0; j < 3; ++j) {                                                     \
            int row = nw * 48 + j * 16 + fr;                                              \
            int g0 = ks * 8 + kg * 2;                                                     \
            float4 lo = *(const float4*)&ldsB[CUR][row * 64 + ((g0 ^ fr) * 4)];           \
            float4 hi = *(const float4*)&ldsB[CUR][row * 64 + (((g0 + 1) ^ fr) * 4)];     \
            uint2 ca = cvt4(lo), cb = cvt4(hi);                                           \
            bfr[j] = __builtin_bit_cast(short8, make_uint4(ca.x, ca.y, cb.x, cb.y));      \
        }                                                                                 \
        _Pragma("unroll")                                                                 \
        for (int i = 0; i < 2; ++i) {                                                     \
            short8 af = *(const short8*)&ldsA[CUR][((mw * 2 + i) * 2 + ks) * 512 + lane * 8]; \
            _Pragma("unroll")                                                             \
            for (int j = 0; j < 3; ++j)                                                   \
                acc[i][j] = __builtin_amdgcn_mfma_f32_16x16x32_bf16(af, bfr[j], acc[i][j], 0, 0, 0); \
        }                                                                                 \
    }                                                                                     \
} while (0)

#define BODY(T, CUR, ISSUE, VMC) do {                                                     \
    __builtin_amdgcn_s_barrier();                                                         \
    __builtin_amdgcn_sched_barrier(0);                                                    \
    if (ISSUE) { STAGE(((T) + 2) % 3, (T) + 2); }                                         \
    __builtin_amdgcn_sched_barrier(0);                                                    \
    asm volatile("s_waitcnt vmcnt(" VMC ")" ::: "memory");                                \
    __builtin_amdgcn_sched_barrier(0);                                                    \
    __builtin_amdgcn_s_barrier();                                                         \
    __builtin_amdgcn_sched_barrier(0);                                                    \
    COMPUTE(CUR);                                                                         \
} while (0)

    STAGE(0, 0);
    STAGE(1, 1);
#pragma unroll 1
    for (int t = 0; t < NSTEP - 2; t += 3) {
        BODY(t,     0, 1, "10");
        BODY(t + 1, 1, 1, "10");
        BODY(t + 2, 2, 1, "10");
    }
    BODY(NSTEP - 2, 0, 0, "5");
    BODY(NSTEP - 1, 1, 0, "0");
#undef BODY
#undef COMPUTE
#undef STAGE

#pragma unroll
    for (int i = 0; i < 2; ++i)
#pragma unroll
        for (int j = 0; j < 3; ++j)
#pragma unroll
            for (int r = 0; r < 4; ++r)
                C[(size_t)(bm + mw * 32 + i * 16 + kg * 4 + r) * NPROXY + (bn + nw * 48 + j * 16 + fr)] = acc[i][j][r];
}

// ---------------- per-sample (fused finalize): 12 block reductions, all 32-bit ----------------
__device__ __forceinline__ float block_sum_f(float x, volatile float* red8, int lane, int wid) {
#pragma unroll
    for (int off = 32; off; off >>= 1) x += __shfl_xor(x, off);
    if (lane == 0) red8[wid] = x;
    __syncthreads();
    float t = 0.f;
#pragma unroll
    for (int w = 0; w < 8; ++w) t += red8[w];
    __syncthreads();
    return t;
}
__device__ __forceinline__ float2 block_max2_f(float a, float b, volatile float* red16, int lane, int wid) {
#pragma unroll
    for (int off = 32; off; off >>= 1) {
        a = fmaxf(a, __shfl_xor(a, off));
        b = fmaxf(b, __shfl_xor(b, off));
    }
    if (lane == 0) { red16[wid * 2] = a; red16[wid * 2 + 1] = b; }
    __syncthreads();
    float ta = -1e30f, tb = -1e30f;
#pragma unroll
    for (int w = 0; w < 8; ++w) {
        ta = fmaxf(ta, red16[w * 2]);
        tb = fmaxf(tb, red16[w * 2 + 1]);
    }
    __syncthreads();
    return make_float2(ta, tb);
}
__device__ __forceinline__ unsigned block_sum_u32(unsigned x, volatile unsigned* red8, int lane, int wid) {
#pragma unroll
    for (int off = 32; off; off >>= 1) x += __shfl_xor(x, off);
    if (lane == 0) red8[wid] = x;
    __syncthreads();
    unsigned t = 0;
#pragma unroll
    for (int w = 0; w < 8; ++w) t += red8[w];
    __syncthreads();
    return t;
}

__global__ __launch_bounds__(512) void per_sample(const float* __restrict__ sims,  // [256][12000]
                                                  const int* __restrict__ cams,
                                                  const int* __restrict__ labels,
                                                  float* __restrict__ loss_acc,    // [6]
                                                  unsigned* __restrict__ cnt_acc,  // [6]
                                                  unsigned* __restrict__ ticket,   // [1]
                                                  float* __restrict__ out)
{
    __shared__ float red16[16];
    __shared__ unsigned redu[8];
    __shared__ float pos_sh[N_CAMS];
    __shared__ float sh_vlab;

    const int i    = blockIdx.x;
    const int tid  = threadIdx.x;
    const int lane = tid & 63;
    const int wid  = tid >> 6;
    const float* s = sims + (size_t)i * NPROXY;
    const int cc   = cams[i];
    const int lab  = labels[i];

    float4 v[6];
#pragma unroll
    for (int ii = 0; ii < 6; ++ii) {
        int q = tid + 512 * ii;
        if (q < NPROXY / 4) v[ii] = *(const float4*)(s + 4 * q);
        else v[ii] = make_float4(-1e30f, -1e30f, -1e30f, -1e30f);
    }

    // ---- capture label value, capture positives, mask in-register (one pass) ----
    const int plab = cc * CLS + lab;
    const int qlab = plab >> 2, clab = plab & 3;
#pragma unroll
    for (int ii = 0; ii < 6; ++ii) {
        if ((qlab >> 9) == ii && (qlab & 511) == tid) {
            float t = (clab == 0) ? v[ii].x : (clab == 1) ? v[ii].y : (clab == 2) ? v[ii].z : v[ii].w;
            sh_vlab = t;
        }
    }
#define DOPC(II, COMP, CIDX) { \
        int p = 4 * (tid + 512 * (II)) + (CIDX); \
        int r = p - lab; \
        if (r >= 0 && r <= (N_CAMS - 1) * CLS && (r % CLS) == 0) { \
            pos_sh[r / CLS] = v[II].COMP; \
            v[II].COMP = MASK_VAL; \
        } }
#pragma unroll
    for (int ii = 0; ii < 6; ++ii) {
        DOPC(ii, x, 0); DOPC(ii, y, 1); DOPC(ii, z, 2); DOPC(ii, w, 3);
    }
#undef DOPC
    __syncthreads();   // sh_vlab + pos_sh visible

    // ---- fused dual max: own-camera masked max & global masked max ----
    const int qlo = cc * 500, qhi = qlo + 500;
    float mo = -1e30f, mg = -1e30f;
#pragma unroll
    for (int ii = 0; ii < 6; ++ii) {
        int q = tid + 512 * ii;
        float mx = fmaxf(fmaxf(v[ii].x, v[ii].y), fmaxf(v[ii].z, v[ii].w));
        mg = fmaxf(mg, mx);
        if (q >= qlo && q < qhi) mo = fmaxf(mo, mx);
    }
    const float2 mr = block_max2_f(mo, mg, red16, lane, wid);
    const float vlab = sh_vlab;
    const float smax = fmaxf(mr.x, vlab);    // unmasked own-block max (label slot re-added)
    const float M1   = mr.y;                 // masked global max

    // ---- CE sum over own block (masked sum + analytic label term) ----
    float ls = 0.f;
#pragma unroll
    for (int ii = 0; ii < 6; ++ii) {
        int q = tid + 512 * ii;
        if (q >= qlo && q < qhi) {
            ls += __expf((v[ii].x - smax) * BETA_INV);   // masked slot -> 0
            ls += __expf((v[ii].y - smax) * BETA_INV);
            ls += __expf((v[ii].z - smax) * BETA_INV);
            ls += __expf((v[ii].w - smax) * BETA_INV);
        }
    }
    const float lsum = block_sum_f(ls, red16, lane, wid);
    float ce_val = 0.f;
    if (tid == 0)
        ce_val = logf(lsum + __expf((vlab - smax) * BETA_INV)) + (smax - vlab) * BETA_INV;

    float pmax = -1e30f, psum = 0.f;
#pragma unroll
    for (int j = 0; j < N_CAMS; ++j) {
        float pv = pos_sh[j];
        pmax = fmaxf(pmax, pv);
        psum += pv;
    }

    // ---- 9-round ternary search for 50th-largest (2 thresholds/round, u32-packed) ----
    float lo = M1 - 0.5f, hi = M1 + 1e-4f;
    int cnt_hi = 0;
    for (int it = 0; it < 9; ++it) {
        const float w3 = (hi - lo) * (1.0f / 3.0f);
        const float t1 = lo + w3, t2 = lo + 2.f * w3;
        unsigned p = 0;
#pragma unroll
        for (int ii = 0; ii < 6; ++ii) {
#define DOC(COMP) { float x = v[ii].COMP; \
            if (x >= t1) p += 1u; \
            if (x >= t2) p += (1u << 16); }
            DOC(x) DOC(y) DOC(z) DOC(w)
#undef DOC
        }
        p = block_sum_u32(p, redu, lane, wid);
        const int C1 = (int)(p & 0xFFFF);
        const int C2 = (int)(p >> 16);
        if (C2 >= BG_KNN)      { lo = t2; }
        else if (C1 >= BG_KNN) { lo = t1; hi = t2; cnt_hi = C2; }
        else                   { hi = t1; cnt_hi = C1; }
    }

    // ---- final: sum exp over top-50 (ties at lo; band width 2.5e-5 -> negligible) ----
    const float M = fmaxf(M1, pmax);
    float ss = 0.f;
#pragma unroll
    for (int ii = 0; ii < 6; ++ii) {
#define DOF(COMP) { float x = v[ii].COMP; \
        if (x >= hi) ss += __expf((x - M) * BETA_INV); }
        DOF(x) DOF(y) DOF(z) DOF(w)
#undef DOF
    }
    const float ssum = block_sum_f(ss, red16, lane, wid);

    if (tid == 0) {
        int need = BG_KNN - cnt_hi;
        float total = ssum + (float)need * __expf((lo - M) * BETA_INV);
#pragma unroll
        for (int j = 0; j < N_CAMS; ++j) total += __expf((pos_sh[j] - M) * BETA_INV);
        float assoc = M * BETA_INV + logf(total) - psum * BETA_INV / (float)N_CAMS;

        // ---- fused finalize: per-camera atomic accumulation + last-block reduce ----
        atomicAdd(&loss_acc[cc], ce_val + 0.5f * assoc);
        atomicAdd(&cnt_acc[cc], 1u);
        __threadfence();
        unsigned tk = atomicAdd(ticket, 1u);
        if (tk == BATCH - 1) {
            float loss = 0.f;
#pragma unroll
            for (int k = 0; k < N_CAMS; ++k) {
                unsigned n = atomicAdd(&cnt_acc[k], 0u);
                if (n > 0) loss += atomicAdd(&loss_acc[k], 0.0f) / (float)n;
            }
            out[0] = loss;
        }
    }
}

extern "C" void kernel_launch(void* const* d_in, const int* in_sizes, int n_in,
                              void* d_out, int out_size, void* d_ws, size_t ws_size,
                              hipStream_t stream) {
    const float* feats  = (const float*)d_in[0];   // [256][2048]
    const float* mem    = (const float*)d_in[1];   // [6][2000][2048]
    const int*   cams   = (const int*)d_in[2];
    const int*   labels = (const int*)d_in[3];
    float* out = (float*)d_out;

    float* sims  = (float*)d_ws;                                // [256][12000] = 12.3 MB
    unsigned short* At = (unsigned short*)(sims + (size_t)BATCH * NPROXY);   // 1 MB frag layout
    float*    loss_acc = (float*)(At + (size_t)BATCH * DIM);    // [6]
    unsigned* cnt_acc  = (unsigned*)(loss_acc + N_CAMS);        // [6]
    unsigned* ticket   = cnt_acc + N_CAMS;                      // [1]

    conv_t<<<(BATCH / 32) * (DIM / 64), 256, 0, stream>>>(feats, At, BATCH / 32, (unsigned*)loss_acc);
    gemm_fullk<<<250, 512, 0, stream>>>(At, mem, sims);
    per_sample<<<BATCH, 512, 0, stream>>>(sims, cams, labels, loss_acc, cnt_acc, ticket, out);
}

// Round 20
// 57.158 us; speedup vs baseline: 1.1690x; 1.1690x over previous
//
#include <hip/hip_runtime.h>
#include <hip/hip_bf16.h>
#include <math.h>

#define BETA_INV 20.0f          // 1/0.05
#define BG_KNN   50
#define N_CAMS   6
#define CLS      2000
#define DIM      2048
#define BATCH    256
#define NPROXY   (N_CAMS * CLS)     // 12000
#define MASK_VAL -10000.0f
#define NKT      (DIM / 32)         // 64 K-tiles of 32

typedef __attribute__((ext_vector_type(8))) short short8;
typedef __attribute__((ext_vector_type(4))) float f32x4;
typedef __attribute__((address_space(1))) const unsigned int g_u32;
typedef __attribute__((address_space(3))) unsigned int l_u32;

__device__ __forceinline__ uint2 cvt4(float4 v) {
    uint2 r;
    asm("v_cvt_pk_bf16_f32 %0, %1, %2" : "=v"(r.x) : "v"(v.x), "v"(v.y));
    asm("v_cvt_pk_bf16_f32 %0, %1, %2" : "=v"(r.y) : "v"(v.z), "v"(v.w));
    return r;
}

// ---------------- transpose fp32 [rows][2048] -> bf16 MFMA-fragment layout ----------------
__global__ __launch_bounds__(256) void conv_t(const float* __restrict__ src,
                                              unsigned short* __restrict__ dst,
                                              int nrb)   // rows/32
{
    __shared__ unsigned short lds[32][72];
    const int t  = threadIdx.x;
    const int b  = blockIdx.x;
    const int rb = b % nrb, kb = b / nrb;
    const int r  = t >> 3, c8 = (t & 7) * 8;

    const float* sp = src + (size_t)(rb * 32 + r) * DIM + kb * 64 + c8;
    float4 f0 = *(const float4*)sp;
    float4 f1 = *(const float4*)(sp + 4);
    uint2 pa = cvt4(f0), pb = cvt4(f1);
    *(uint4*)&lds[r][c8] = make_uint4(pa.x, pa.y, pb.x, pb.y);
    __syncthreads();

    const int cidx = t >> 6;
    const int n16h = cidx >> 1, kth = cidx & 1;
    const int lane = t & 63;
    const int fr = lane & 15, kg = lane >> 4;
    uint4 v = *(const uint4*)&lds[n16h * 16 + fr][kth * 32 + kg * 8];
    const size_t N16 = (size_t)rb * 2 + n16h;
    const size_t KT  = (size_t)kb * 2 + kth;
    *(uint4*)(dst + ((N16 * NKT + KT) * 64 + lane) * 8) = v;
}

// ---------------- GEMM: BM=128 x BN=96, FULL K, grid 250, ring-3 depth-2 (R15 best) ----
#define NSTEP 32                // 2048 / 64

__global__ __launch_bounds__(512) void gemm_fullk(const unsigned short* __restrict__ At,
                                                  const float* __restrict__ Bm,   // [12000][2048] f32
                                                  float* __restrict__ C)          // [256][12000]
{
    __shared__ __align__(16) unsigned short ldsA[3][8192];   // 3 x 16KB
    __shared__ __align__(16) float          ldsB[3][6144];   // 3 x 24KB

    const int tid = threadIdx.x;
    const int bid = blockIdx.x;
    const int xcd = bid & 7, pos = bid >> 3;
    const int lid = (xcd < 2 ? xcd * 32 : 64 + (xcd - 2) * 31) + pos;
    const int bm  = (lid & 1) * 128;
    const int bn  = (lid >> 1) * 96;

    const int lane = tid & 63, wid = tid >> 6;
    const int mw = wid >> 1;
    const int nw = wid & 1;
    const int fr = lane & 15, kg = lane >> 4;

    const unsigned short* pAq[2];
    int dA[2];
#pragma unroll
    for (int q = 0; q < 2; ++q) {
        int f = q * 512 + tid;
        int chunk = f >> 6, ln = f & 63;
        int n16l = chunk >> 1, ktl = chunk & 1;
        pAq[q] = At + ((size_t)((bm >> 4) + n16l) * NKT + ktl) * 512 + ln * 8;
        dA[q] = f * 8;                // shorts
    }
    const float* pBq[3];
    int dB[3];
#pragma unroll
    for (int q = 0; q < 3; ++q) {
        int f = q * 512 + tid;
        int row = f >> 4, c = f & 15;
        pBq[q] = Bm + (size_t)(bn + row) * DIM + ((c ^ (row & 15)) * 4);
        dB[q] = f * 4;                // floats
    }

#define STAGE(BUF, T) do {                                                                \
        _Pragma("unroll")                                                                 \
        for (int q = 0; q < 2; ++q)                                                       \
            __builtin_amdgcn_global_load_lds((g_u32*)(pAq[q] + (size_t)(T) * 1024),       \
                                             (l_u32*)&ldsA[BUF][dA[q]], 16, 0, 0);        \
        _Pragma("unroll")                                                                 \
        for (int q = 0; q < 3; ++q)                                                       \
            __builtin_amdgcn_global_load_lds((g_u32*)(pBq[q] + (size_t)(T) * 64),         \
                                             (l_u32*)&ldsB[BUF][dB[q]], 16, 0, 0);        \
    } while (0)

    f32x4 acc[2][3];
#pragma unroll
    for (int i = 0; i < 2; ++i)
#pragma unroll
        for (int j = 0; j < 3; ++j) acc[i][j] = (f32x4){0.f, 0.f, 0.f, 0.f};

#define COMPUTE(CUR) do {                                                                 \
    _Pragma("unroll")                                                                     \
    for (int ks = 0; ks < 2; ++ks) {                                                      \
        short8 bfr[3];                                                                    \
        _Pragma("unroll")                                                                 \
        for (int j = 0; j < 3; ++j) {                                                     \
            int row = nw * 48 + j * 16 + fr;                                              \
            int g0 = ks * 8 + kg * 2;                                                     \
            float4 lo = *(const float4*)&ldsB[CUR][row * 64 + ((g0 ^ fr) * 4)];           \
            float4 hi = *(const float4*)&ldsB[CUR][row * 64 + (((g0 + 1) ^ fr) * 4)];     \
            uint2 ca = cvt4(lo), cb = cvt4(hi);                                           \
            bfr[j] = __builtin_bit_cast(short8, make_uint4(ca.x, ca.y, cb.x, cb.y));      \
        }                                                                                 \
        _Pragma("unroll")                                                                 \
        for (int i = 0; i < 2; ++i) {                                                     \
            short8 af = *(const short8*)&ldsA[CUR][((mw * 2 + i) * 2 + ks) * 512 + lane * 8]; \
            _Pragma("unroll")                                                             \
            for (int j = 0; j < 3; ++j)                                                   \
                acc[i][j] = __builtin_amdgcn_mfma_f32_16x16x32_bf16(af, bfr[j], acc[i][j], 0, 0, 0); \
        }                                                                                 \
    }                                                                                     \
} while (0)

#define BODY(T, CUR, ISSUE, VMC) do {                                                     \
    __builtin_amdgcn_s_barrier();                                                         \
    __builtin_amdgcn_sched_barrier(0);                                                    \
    if (ISSUE) { STAGE(((T) + 2) % 3, (T) + 2); }                                         \
    __builtin_amdgcn_sched_barrier(0);                                                    \
    asm volatile("s_waitcnt vmcnt(" VMC ")" ::: "memory");                                \
    __builtin_amdgcn_sched_barrier(0);                                                    \
    __builtin_amdgcn_s_barrier();                                                         \
    __builtin_amdgcn_sched_barrier(0);                                                    \
    COMPUTE(CUR);                                                                         \
} while (0)

    STAGE(0, 0);
    STAGE(1, 1);
#pragma unroll 1
    for (int t = 0; t < NSTEP - 2; t += 3) {
        BODY(t,     0, 1, "10");
        BODY(t + 1, 1, 1, "10");
        BODY(t + 2, 2, 1, "10");
    }
    BODY(NSTEP - 2, 0, 0, "5");
    BODY(NSTEP - 1, 1, 0, "0");
#undef BODY
#undef COMPUTE
#undef STAGE

#pragma unroll
    for (int i = 0; i < 2; ++i)
#pragma unroll
        for (int j = 0; j < 3; ++j)
#pragma unroll
            for (int r = 0; r < 4; ++r)
                C[(size_t)(bm + mw * 32 + i * 16 + kg * 4 + r) * NPROXY + (bn + nw * 48 + j * 16 + fr)] = acc[i][j][r];
}

// ---------------- per-sample: 12 block reductions, all 32-bit ----------------
__device__ __forceinline__ float block_sum_f(float x, volatile float* red8, int lane, int wid) {
#pragma unroll
    for (int off = 32; off; off >>= 1) x += __shfl_xor(x, off);
    if (lane == 0) red8[wid] = x;
    __syncthreads();
    float t = 0.f;
#pragma unroll
    for (int w = 0; w < 8; ++w) t += red8[w];
    __syncthreads();
    return t;
}
__device__ __forceinline__ float2 block_max2_f(float a, float b, volatile float* red16, int lane, int wid) {
#pragma unroll
    for (int off = 32; off; off >>= 1) {
        a = fmaxf(a, __shfl_xor(a, off));
        b = fmaxf(b, __shfl_xor(b, off));
    }
    if (lane == 0) { red16[wid * 2] = a; red16[wid * 2 + 1] = b; }
    __syncthreads();
    float ta = -1e30f, tb = -1e30f;
#pragma unroll
    for (int w = 0; w < 8; ++w) {
        ta = fmaxf(ta, red16[w * 2]);
        tb = fmaxf(tb, red16[w * 2 + 1]);
    }
    __syncthreads();
    return make_float2(ta, tb);
}
__device__ __forceinline__ unsigned block_sum_u32(unsigned x, volatile unsigned* red8, int lane, int wid) {
#pragma unroll
    for (int off = 32; off; off >>= 1) x += __shfl_xor(x, off);
    if (lane == 0) red8[wid] = x;
    __syncthreads();
    unsigned t = 0;
#pragma unroll
    for (int w = 0; w < 8; ++w) t += red8[w];
    __syncthreads();
    return t;
}

__global__ __launch_bounds__(512) void per_sample(const float* __restrict__ sims,  // [256][12000]
                                                  const int* __restrict__ cams,
                                                  const int* __restrict__ labels,
                                                  float* __restrict__ ce_out,
                                                  float* __restrict__ assoc_out)
{
    __shared__ float red16[16];
    __shared__ unsigned redu[8];
    __shared__ float pos_sh[N_CAMS];
    __shared__ float sh_vlab;

    const int i    = blockIdx.x;
    const int tid  = threadIdx.x;
    const int lane = tid & 63;
    const int wid  = tid >> 6;
    const float* s = sims + (size_t)i * NPROXY;
    const int cc   = cams[i];
    const int lab  = labels[i];

    float4 v[6];
#pragma unroll
    for (int ii = 0; ii < 6; ++ii) {
        int q = tid + 512 * ii;
        if (q < NPROXY / 4) v[ii] = *(const float4*)(s + 4 * q);
        else v[ii] = make_float4(-1e30f, -1e30f, -1e30f, -1e30f);
    }

    // ---- capture label value, capture positives, mask in-register (one pass) ----
    const int plab = cc * CLS + lab;
    const int qlab = plab >> 2, clab = plab & 3;
#pragma unroll
    for (int ii = 0; ii < 6; ++ii) {
        if ((qlab >> 9) == ii && (qlab & 511) == tid) {
            float t = (clab == 0) ? v[ii].x : (clab == 1) ? v[ii].y : (clab == 2) ? v[ii].z : v[ii].w;
            sh_vlab = t;
        }
    }
#define DOPC(II, COMP, CIDX) { \
        int p = 4 * (tid + 512 * (II)) + (CIDX); \
        int r = p - lab; \
        if (r >= 0 && r <= (N_CAMS - 1) * CLS && (r % CLS) == 0) { \
            pos_sh[r / CLS] = v[II].COMP; \
            v[II].COMP = MASK_VAL; \
        } }
#pragma unroll
    for (int ii = 0; ii < 6; ++ii) {
        DOPC(ii, x, 0); DOPC(ii, y, 1); DOPC(ii, z, 2); DOPC(ii, w, 3);
    }
#undef DOPC
    __syncthreads();   // sh_vlab + pos_sh visible

    // ---- fused dual max: own-camera masked max & global masked max ----
    const int qlo = cc * 500, qhi = qlo + 500;
    float mo = -1e30f, mg = -1e30f;
#pragma unroll
    for (int ii = 0; ii < 6; ++ii) {
        int q = tid + 512 * ii;
        float mx = fmaxf(fmaxf(v[ii].x, v[ii].y), fmaxf(v[ii].z, v[ii].w));
        mg = fmaxf(mg, mx);
        if (q >= qlo && q < qhi) mo = fmaxf(mo, mx);
    }
    const float2 mr = block_max2_f(mo, mg, red16, lane, wid);
    const float vlab = sh_vlab;
    const float smax = fmaxf(mr.x, vlab);    // unmasked own-block max (label slot re-added)
    const float M1   = mr.y;                 // masked global max

    // ---- CE sum over own block (masked sum + analytic label term) ----
    float ls = 0.f;
#pragma unroll
    for (int ii = 0; ii < 6; ++ii) {
        int q = tid + 512 * ii;
        if (q >= qlo && q < qhi) {
            ls += __expf((v[ii].x - smax) * BETA_INV);   // masked slot -> 0
            ls += __expf((v[ii].y - smax) * BETA_INV);
            ls += __expf((v[ii].z - smax) * BETA_INV);
            ls += __expf((v[ii].w - smax) * BETA_INV);
        }
    }
    const float lsum = block_sum_f(ls, red16, lane, wid);
    if (tid == 0)
        ce_out[i] = logf(lsum + __expf((vlab - smax) * BETA_INV)) + (smax - vlab) * BETA_INV;

    float pmax = -1e30f, psum = 0.f;
#pragma unroll
    for (int j = 0; j < N_CAMS; ++j) {
        float pv = pos_sh[j];
        pmax = fmaxf(pmax, pv);
        psum += pv;
    }

    // ---- 9-round ternary search for 50th-largest (2 thresholds/round, u32-packed) ----
    float lo = M1 - 0.5f, hi = M1 + 1e-4f;
    int cnt_hi = 0;
    for (int it = 0; it < 9; ++it) {
        const float w3 = (hi - lo) * (1.0f / 3.0f);
        const float t1 = lo + w3, t2 = lo + 2.f * w3;
        unsigned p = 0;
#pragma unroll
        for (int ii = 0; ii < 6; ++ii) {
#define DOC(COMP) { float x = v[ii].COMP; \
            if (x >= t1) p += 1u; \
            if (x >= t2) p += (1u << 16); }
            DOC(x) DOC(y) DOC(z) DOC(w)
#undef DOC
        }
        p = block_sum_u32(p, redu, lane, wid);
        const int C1 = (int)(p & 0xFFFF);
        const int C2 = (int)(p >> 16);
        if (C2 >= BG_KNN)      { lo = t2; }
        else if (C1 >= BG_KNN) { lo = t1; hi = t2; cnt_hi = C2; }
        else                   { hi = t1; cnt_hi = C1; }
    }

    // ---- final: sum exp over top-50 (ties at lo; band width 2.5e-5 -> negligible) ----
    const float M = fmaxf(M1, pmax);
    float ss = 0.f;
#pragma unroll
    for (int ii = 0; ii < 6; ++ii) {
#define DOF(COMP) { float x = v[ii].COMP; \
        if (x >= hi) ss += __expf((x - M) * BETA_INV); }
        DOF(x) DOF(y) DOF(z) DOF(w)
#undef DOF
    }
    const float ssum = block_sum_f(ss, red16, lane, wid);

    if (tid == 0) {
        int need = BG_KNN - cnt_hi;
        float total = ssum + (float)need * __expf((lo - M) * BETA_INV);
#pragma unroll
        for (int j = 0; j < N_CAMS; ++j) total += __expf((pos_sh[j] - M) * BETA_INV);
        assoc_out[i] = M * BETA_INV + logf(total) - psum * BETA_INV / (float)N_CAMS;
    }
}

// ---------------- Finalize ----------------
__global__ __launch_bounds__(256) void finalize(const int* __restrict__ cams,
                                                const float* __restrict__ ce,
                                                const float* __restrict__ assoc,
                                                float* __restrict__ out)
{
    __shared__ float ce_s[N_CAMS], as_s[N_CAMS];
    __shared__ int   cnt[N_CAMS];
    const int tid = threadIdx.x;
    if (tid < N_CAMS) { ce_s[tid] = 0.f; as_s[tid] = 0.f; cnt[tid] = 0; }
    __syncthreads();
    const int c = cams[tid];
    atomicAdd(&ce_s[c], ce[tid]);
    atomicAdd(&as_s[c], assoc[tid]);
    atomicAdd(&cnt[c], 1);
    __syncthreads();
    if (tid == 0) {
        float loss = 0.f;
        for (int k = 0; k < N_CAMS; ++k) {
            if (cnt[k] > 0) {
                float inv = 1.f / (float)cnt[k];
                loss += ce_s[k] * inv + 0.5f * as_s[k] * inv;
            }
        }
        out[0] = loss;
    }
}

extern "C" void kernel_launch(void* const* d_in, const int* in_sizes, int n_in,
                              void* d_out, int out_size, void* d_ws, size_t ws_size,
                              hipStream_t stream) {
    const float* feats  = (const float*)d_in[0];   // [256][2048]
    const float* mem    = (const float*)d_in[1];   // [6][2000][2048]
    const int*   cams   = (const int*)d_in[2];
    const int*   labels = (const int*)d_in[3];
    float* out = (float*)d_out;

    float* sims  = (float*)d_ws;                                // [256][12000] = 12.3 MB
    float* ce    = sims + (size_t)BATCH * NPROXY;
    float* assoc = ce + BATCH;
    unsigned short* At = (unsigned short*)(assoc + BATCH);      // 1 MB frag layout

    conv_t<<<(BATCH / 32) * (DIM / 64), 256, 0, stream>>>(feats, At, BATCH / 32);   // 256 blocks
    gemm_fullk<<<250, 512, 0, stream>>>(At, mem, sims);
    per_sample<<<BATCH, 512, 0, stream>>>(sims, cams, labels, ce, assoc);
    finalize<<<1, 256, 0, stream>>>(cams, ce, assoc, out);
}